// Round 8
// baseline (1603.643 us; speedup 1.0000x reference)
//
#include <hip/hip_runtime.h>
#include <hip/hip_bf16.h>
#include <math.h>

#define N_NODES 65536
#define N_EDGES 1048576
#define NB      32
#define D       64
#define NLAYERS 4
#define G       16     // dst nodes per block (4 per wave)
#define EC      16     // edges per wave-chunk
#define AST     72     // ushort stride for bf16 LDS activation arrays (16B-aligned rows)
#define PST     68     // float stride for p / p*M overlay arrays

typedef __attribute__((ext_vector_type(8))) short short8;   // 8 bf16 in 4 VGPRs
typedef __attribute__((ext_vector_type(4))) float f32x4;

__device__ __forceinline__ float relu_f(float x){ return x > 0.f ? x : 0.f; }
__device__ __forceinline__ unsigned short bfbits(float x){
    __bf16 h = (__bf16)x;
    return __builtin_bit_cast(unsigned short, h);
}
__device__ __forceinline__ float bfval(float x){     // value after bf16 rounding
    __bf16 h = (__bf16)x;
    return (float)h;
}
__device__ __forceinline__ f32x4 mfma16(short8 a, short8 b, f32x4 c){
    return __builtin_amdgcn_mfma_f32_16x16x32_bf16(a, b, c, 0, 0, 0);
}

// ---------------- sort-by-dst machinery ----------------

__global__ void k_zero(int* __restrict__ p){
    p[blockIdx.x * 256 + threadIdx.x] = 0;
}

__global__ void k_hist(const int* __restrict__ dst, int* __restrict__ deg){
    int e = blockIdx.x * 256 + threadIdx.x;
    if (e < N_EDGES) atomicAdd(&deg[dst[e]], 1);
}

__global__ void k_scan1(const int* __restrict__ deg, int* __restrict__ part, int* __restrict__ bsum){
    __shared__ int s[256];
    int t = threadIdx.x;
    int i = blockIdx.x * 256 + t;
    int v = deg[i];
    s[t] = v; __syncthreads();
    for (int ofs = 1; ofs < 256; ofs <<= 1){
        int tv = (t >= ofs) ? s[t - ofs] : 0;
        __syncthreads();
        s[t] += tv;
        __syncthreads();
    }
    part[i] = s[t] - v;
    if (t == 255) bsum[blockIdx.x] = s[255];
}

__global__ void k_scan2(const int* __restrict__ bsum, int* __restrict__ bofs){
    __shared__ int s[256];
    int t = threadIdx.x;
    int v = bsum[t];
    s[t] = v; __syncthreads();
    for (int ofs = 1; ofs < 256; ofs <<= 1){
        int tv = (t >= ofs) ? s[t - ofs] : 0;
        __syncthreads();
        s[t] += tv;
        __syncthreads();
    }
    bofs[t] = s[t] - v;
}

__global__ void k_scan3(const int* __restrict__ part, const int* __restrict__ bofs,
                        int* __restrict__ off, int* __restrict__ cursor){
    int i = blockIdx.x * 256 + threadIdx.x;
    int o = part[i] + bofs[i >> 8];
    off[i] = o; cursor[i] = o;
    if (i == 0) off[N_NODES] = N_EDGES;
}

__global__ void k_scatter(const int* __restrict__ ei, const float* __restrict__ pos,
                          int* __restrict__ cursor, int* __restrict__ srcs,
                          float* __restrict__ pdb){
    int e = blockIdx.x * 256 + threadIdx.x;
    if (e >= N_EDGES) return;
    int s = ei[e], d = ei[N_EDGES + e];
    int p = atomicAdd(&cursor[d], 1);
    srcs[p]    = s;
    pdb[2*p]   = pos[2*d]   - pos[2*s];
    pdb[2*p+1] = pos[2*d+1] - pos[2*s+1];
}

// ---------------- weight pre-pack into MFMA B-fragment order (hi/lo) ----------------
// Per layer block (24576 ushort): [hl][mat][nb][kf][lane][8], hl-stride 12288.
// B-frag: lane holds B[k = kf*32 + (lane>>4)*8 + j][n = nb*16 + (lane&15)], j=0..7.

__global__ void k_pack(const float* __restrict__ pW2, const float* __restrict__ aW1,
                       const float* __restrict__ aW2, unsigned short* __restrict__ bpk){
    int b  = blockIdx.x;                // L*24 + mat*8 + nb*2 + kf
    int kf = b & 1, nb = (b >> 1) & 3;
    int mat = (b >> 3) % 3, L = b / 24;
    int t = threadIdx.x;
    int lane = t & 63, jj = (t >> 6) * 2;
    const float* W = (mat == 0 ? pW2 : (mat == 1 ? aW1 : aW2)) + (size_t)L * D * D;
    int n = nb * 16 + (lane & 15);
    unsigned short* dsthi = bpk + (size_t)L * 24576
                          + (((size_t)mat * 4 + nb) * 2 + kf) * 512 + lane * 8 + jj;
    #pragma unroll
    for (int u = 0; u < 2; ++u){
        int j = jj + u;
        int k = kf * 32 + (lane >> 4) * 8 + j;
        float w = W[k * D + n];
        float hv = bfval(w);
        dsthi[u]         = bfbits(w);
        dsthi[12288 + u] = bfbits(w - hv);
    }
}

// ---------------- node GEMM: v / a_s / a_d = h @ {Wl, Ws, Wd} (fp32 VALU) ----------------

__global__ __launch_bounds__(256) void k_nodegemm(
    const float* __restrict__ h,
    const float* __restrict__ Wl, const float* __restrict__ Ws, const float* __restrict__ Wd,
    float* __restrict__ v, float* __restrict__ as_, float* __restrict__ ad)
{
    __shared__ float HT[D * 68];
    int row0 = blockIdx.x * 64;
    int t = threadIdx.x;
    {
        int r  = t >> 2;
        int kb = (t & 3) * 16;
        const float4* hp = (const float4*)(h + (size_t)(row0 + r) * D + kb);
        #pragma unroll
        for (int i4 = 0; i4 < 4; ++i4){
            float4 a = hp[i4];
            HT[(kb + i4*4 + 0)*68 + r] = a.x;
            HT[(kb + i4*4 + 1)*68 + r] = a.y;
            HT[(kb + i4*4 + 2)*68 + r] = a.z;
            HT[(kb + i4*4 + 3)*68 + r] = a.w;
        }
    }
    __syncthreads();
    int tr = t >> 4, tc = t & 15;
    int r0 = tr * 4, c0 = tc * 4;
    float accl[4][4] = {}, accs[4][4] = {}, accd[4][4] = {};
    #pragma unroll 8
    for (int k = 0; k < D; ++k){
        float4 a  = *(const float4*)&HT[k*68 + r0];
        float4 bl = *(const float4*)(Wl + k*D + c0);
        float4 bs = *(const float4*)(Ws + k*D + c0);
        float4 bd = *(const float4*)(Wd + k*D + c0);
        float av[4] = {a.x, a.y, a.z, a.w};
        #pragma unroll
        for (int i = 0; i < 4; ++i){
            accl[i][0] += av[i]*bl.x; accl[i][1] += av[i]*bl.y;
            accl[i][2] += av[i]*bl.z; accl[i][3] += av[i]*bl.w;
            accs[i][0] += av[i]*bs.x; accs[i][1] += av[i]*bs.y;
            accs[i][2] += av[i]*bs.z; accs[i][3] += av[i]*bs.w;
            accd[i][0] += av[i]*bd.x; accd[i][1] += av[i]*bd.y;
            accd[i][2] += av[i]*bd.z; accd[i][3] += av[i]*bd.w;
        }
    }
    #pragma unroll
    for (int i = 0; i < 4; ++i){
        size_t o = (size_t)(row0 + r0 + i) * D + c0;
        *(float4*)(v  + o) = make_float4(accl[i][0], accl[i][1], accl[i][2], accl[i][3]);
        *(float4*)(as_+ o) = make_float4(accs[i][0], accs[i][1], accs[i][2], accs[i][3]);
        *(float4*)(ad + o) = make_float4(accd[i][0], accd[i][1], accd[i][2], accd[i][3]);
    }
}

// ---------------- fused edge kernel: WAVE-AUTONOMOUS, zero main-loop barriers ----------
// Round-8: rounds 0-7 shared one A-tile across 4 waves -> 6 __syncthreads per chunk,
// each with a compiler-emitted vmcnt(0)/lgkmcnt(0) drain (the m97-style structural
// stall; measured floor ~48% busy). Now each WAVE owns 4 dst nodes and runs the whole
// pipeline on its own 16-edge chunks against wave-PRIVATE LDS:
//   AB: t1 = relu(pd @ pW1 + pb1) -> Thi/Tlo   (wave-local write)
//   C:  GEMM1 (1 m-tile x 4 n-blocks) -> delta; gathers v/as_ (issued first, covered
//       by 24 MFMAs); M = v[src]+delta in regs; u -> Uhi/Ulo
//   D:  GEMM2 -> t2 -> Thi/Tlo (over t1; wave-internal WAR, DS is per-wave in-order)
//   E:  GEMM3 -> alpha; p = exp -> Pf (over u); pm = p*M -> PMf (over t2)
//   F:  per-node reduce den/num from Pf/PMf (wave reads only its own region)
// All LDS deps are wave-internal (in-order DS + data flow) -> NO __syncthreads ->
// no vmcnt drains; waves slide freely (MFMA/VALU co-schedule across waves, m114).
// Work totals, per-cell expression trees and per-node accumulation order are
// IDENTICAL to round 7 -> bit-exact, absmax 0.
// Tell: WRITE_SIZE must stay 16.4 MB / VGPR ~96-120; VGPR=64 + WRITE ballooning
// means the allocator spilled (37KB-LDS precedent) -> split stage C into nb-halves.

__device__ __forceinline__ void load_bfrag(const unsigned short* __restrict__ bpk,
                                           int g, int nb, int lane,
                                           short8& Bh0, short8& Bh1,
                                           short8& Bl0, short8& Bl1)
{
    int bo = ((g*4 + nb)*2)*512 + lane*8;
    asm volatile("" : "+v"(bo));   // defeat LICM/CSE: keep B live-range inside the stage
    Bh0 = __builtin_bit_cast(short8, *(const uint4*)(bpk + bo));
    Bh1 = __builtin_bit_cast(short8, *(const uint4*)(bpk + bo + 512));
    Bl0 = __builtin_bit_cast(short8, *(const uint4*)(bpk + 12288 + bo));
    Bl1 = __builtin_bit_cast(short8, *(const uint4*)(bpk + 12288 + bo + 512));
}

__device__ __forceinline__ f32x4 gemm6(short8 ah0, short8 ah1, short8 al0, short8 al1,
                                       short8 Bh0, short8 Bh1, short8 Bl0, short8 Bl1)
{
    f32x4 acc = {0.f, 0.f, 0.f, 0.f};
    acc = mfma16(ah0, Bh0, acc);
    acc = mfma16(ah1, Bh1, acc);
    acc = mfma16(al0, Bh0, acc);
    acc = mfma16(al1, Bh1, acc);
    acc = mfma16(ah0, Bl0, acc);
    acc = mfma16(ah1, Bl1, acc);
    return acc;
}

__global__ __launch_bounds__(256) void k_edge(
    const int* __restrict__ off, const int* __restrict__ srcs, const float* __restrict__ pdb,
    const float* __restrict__ v, const float* __restrict__ as_, const float* __restrict__ ad,
    const float* __restrict__ pW1, const float* __restrict__ pb1, const float* __restrict__ pb2,
    const float* __restrict__ ab1, const float* __restrict__ ab2,
    const unsigned short* __restrict__ bpk,   // this layer's packed B-frags
    float* __restrict__ hout)
{
    // 4 waves x (t-buf + u-buf) = 4 x 9216 B x 2 halves = 36.9 KB -> 4 blocks/CU
    __shared__ __align__(16) unsigned short ALDS[4 * 2 * EC * AST]; // per-wave t1/t2 hi|lo ; PMf overlay
    __shared__ __align__(16) unsigned short ULDS[4 * 2 * EC * AST]; // per-wave u hi|lo    ; Pf overlay
    __shared__ int s_sp[4 * EC];  // per-wave: src | (node-local l << 16)
    __shared__ int s_off[20];

    int t  = threadIdx.x;
    int n0 = blockIdx.x * G;
    if (t <= G) s_off[t] = off[n0 + t];
    __syncthreads();                    // the ONLY barrier in this kernel

    int w = t >> 6, lane = t & 63;
    int q = lane >> 4, ln = lane & 15;

    unsigned short* Thi = ALDS + w * (2 * EC * AST);
    unsigned short* Tlo = Thi + EC * AST;
    unsigned short* Uhi = ULDS + w * (2 * EC * AST);
    unsigned short* Ulo = Uhi + EC * AST;
    float* Pf  = (float*)Uhi;           // p  overlay (stride PST)
    float* PMf = (float*)Thi;           // pm overlay (stride PST)
    int*   spw = s_sp + w * EC;

    int e_begin = s_off[w*4], e_end = s_off[w*4 + 4];

    float pb2c[4], ab1c[4], ab2c[4];
    #pragma unroll
    for (int nb = 0; nb < 4; ++nb){
        pb2c[nb] = pb2[nb*16 + ln];
        ab1c[nb] = ab1[nb*16 + ln];
        ab2c[nb] = ab2[nb*16 + ln];
    }

    float den[4] = {0.f, 0.f, 0.f, 0.f};
    float num[4] = {0.f, 0.f, 0.f, 0.f};

    for (int ec = e_begin; ec < e_end; ec += EC){
        int cnt = min(EC, e_end - ec);
        // ---- stage AB: edge metadata + t1 -> Thi/Tlo. 4 lanes/edge, 16 ch each.
        {
            if (lane < EC){
                int gg = ec + ((lane < cnt) ? lane : 0);
                int s = srcs[gg];
                int l = 0;
                while (l < 3 && gg >= s_off[w*4 + l + 1]) ++l;
                spw[lane] = s | (l << 16);
            }
            int e8 = lane >> 2, kb = (lane & 3) * 16;
            int g = ec + ((e8 < cnt) ? e8 : 0);
            float2 pd = *(const float2*)(pdb + 2*g);
            float p0 = pd.x, p1 = pd.y;
            unsigned int hw[8], lw[8];
            #pragma unroll
            for (int i4 = 0; i4 < 4; ++i4){
                float4 wa = *(const float4*)(pW1 + kb + i4*4);
                float4 wb = *(const float4*)(pW1 + D + kb + i4*4);
                float4 bb = *(const float4*)(pb1 + kb + i4*4);
                float f0 = relu_f(fmaf(p1, wb.x, fmaf(p0, wa.x, bb.x)));
                float f1 = relu_f(fmaf(p1, wb.y, fmaf(p0, wa.y, bb.y)));
                float f2 = relu_f(fmaf(p1, wb.z, fmaf(p0, wa.z, bb.z)));
                float f3 = relu_f(fmaf(p1, wb.w, fmaf(p0, wa.w, bb.w)));
                hw[i4*2]   = (unsigned int)bfbits(f0) | ((unsigned int)bfbits(f1) << 16);
                hw[i4*2+1] = (unsigned int)bfbits(f2) | ((unsigned int)bfbits(f3) << 16);
                lw[i4*2]   = (unsigned int)bfbits(f0 - bfval(f0)) | ((unsigned int)bfbits(f1 - bfval(f1)) << 16);
                lw[i4*2+1] = (unsigned int)bfbits(f2 - bfval(f2)) | ((unsigned int)bfbits(f3 - bfval(f3)) << 16);
            }
            *(uint4*)&Thi[e8*AST + kb]     = make_uint4(hw[0], hw[1], hw[2], hw[3]);
            *(uint4*)&Thi[e8*AST + kb + 8] = make_uint4(hw[4], hw[5], hw[6], hw[7]);
            *(uint4*)&Tlo[e8*AST + kb]     = make_uint4(lw[0], lw[1], lw[2], lw[3]);
            *(uint4*)&Tlo[e8*AST + kb + 8] = make_uint4(lw[4], lw[5], lw[6], lw[7]);
        }
        // ---- stage C: gathers first (covered by 24 MFMAs), GEMM1 over 4 n-blocks,
        //      epilogue: delta, M, u -> Uhi/Ulo.
        float Mreg[16];
        {
            int sv[4], dl[4];
            #pragma unroll
            for (int r = 0; r < 4; ++r){
                int sp = spw[q*4 + r];
                sv[r] = sp & 0xFFFF;
                dl[r] = sp >> 16;
            }
            float pa[16];
            #pragma unroll
            for (int nb = 0; nb < 4; ++nb)
                #pragma unroll
                for (int r = 0; r < 4; ++r){
                    int c = nb*16 + ln;
                    Mreg[nb*4 + r] = v  [(size_t)sv[r] * D + c];
                    pa  [nb*4 + r] = as_[(size_t)sv[r] * D + c];
                }
            int ro = ln * AST;
            short8 ah0 = __builtin_bit_cast(short8, *(const uint4*)(Thi + ro + q*8));
            short8 ah1 = __builtin_bit_cast(short8, *(const uint4*)(Thi + ro + 32 + q*8));
            short8 al0 = __builtin_bit_cast(short8, *(const uint4*)(Tlo + ro + q*8));
            short8 al1 = __builtin_bit_cast(short8, *(const uint4*)(Tlo + ro + 32 + q*8));
            f32x4 acc[4];
            #pragma unroll
            for (int nb = 0; nb < 4; ++nb){
                short8 Bh0, Bh1, Bl0, Bl1;
                load_bfrag(bpk, 0, nb, lane, Bh0, Bh1, Bl0, Bl1);
                acc[nb] = gemm6(ah0, ah1, al0, al1, Bh0, Bh1, Bl0, Bl1);
            }
            #pragma unroll
            for (int nb = 0; nb < 4; ++nb)
                #pragma unroll
                for (int r = 0; r < 4; ++r){
                    int i = nb*4 + r, e = q*4 + r, c = nb*16 + ln;
                    float dlt = relu_f(acc[nb][r] + pb2c[nb]);
                    int dn = n0 + w*4 + dl[r];
                    float vd = ad[(size_t)dn * D + c];    // 4 rows per wave, L1-hot
                    float uu = vd - pa[i] + dlt;
                    Mreg[i] += dlt;
                    Uhi[e*AST + c] = bfbits(uu);
                    Ulo[e*AST + c] = bfbits(uu - bfval(uu));
                }
        }
        // ---- stage D: GEMM2 (u @ aW1) -> t2 -> Thi/Tlo (over t1; wave-internal WAR)
        {
            int ro = ln * AST;
            short8 ah0 = __builtin_bit_cast(short8, *(const uint4*)(Uhi + ro + q*8));
            short8 ah1 = __builtin_bit_cast(short8, *(const uint4*)(Uhi + ro + 32 + q*8));
            short8 al0 = __builtin_bit_cast(short8, *(const uint4*)(Ulo + ro + q*8));
            short8 al1 = __builtin_bit_cast(short8, *(const uint4*)(Ulo + ro + 32 + q*8));
            f32x4 acc[4];
            #pragma unroll
            for (int nb = 0; nb < 4; ++nb){
                short8 Bh0, Bh1, Bl0, Bl1;
                load_bfrag(bpk, 1, nb, lane, Bh0, Bh1, Bl0, Bl1);
                acc[nb] = gemm6(ah0, ah1, al0, al1, Bh0, Bh1, Bl0, Bl1);
            }
            #pragma unroll
            for (int nb = 0; nb < 4; ++nb)
                #pragma unroll
                for (int r = 0; r < 4; ++r){
                    int e = q*4 + r, c = nb*16 + ln;
                    float t2 = relu_f(acc[nb][r] + ab1c[nb]);
                    Thi[e*AST + c] = bfbits(t2);
                    Tlo[e*AST + c] = bfbits(t2 - bfval(t2));
                }
        }
        // ---- stage E: GEMM3 (t2 @ aW2) -> alpha; p -> Pf (over u); pm -> PMf (over t2)
        {
            int ro = ln * AST;
            short8 ah0 = __builtin_bit_cast(short8, *(const uint4*)(Thi + ro + q*8));
            short8 ah1 = __builtin_bit_cast(short8, *(const uint4*)(Thi + ro + 32 + q*8));
            short8 al0 = __builtin_bit_cast(short8, *(const uint4*)(Tlo + ro + q*8));
            short8 al1 = __builtin_bit_cast(short8, *(const uint4*)(Tlo + ro + 32 + q*8));
            f32x4 acc[4];
            #pragma unroll
            for (int nb = 0; nb < 4; ++nb){
                short8 Bh0, Bh1, Bl0, Bl1;
                load_bfrag(bpk, 2, nb, lane, Bh0, Bh1, Bl0, Bl1);
                acc[nb] = gemm6(ah0, ah1, al0, al1, Bh0, Bh1, Bl0, Bl1);
            }
            #pragma unroll
            for (int nb = 0; nb < 4; ++nb)
                #pragma unroll
                for (int r = 0; r < 4; ++r){
                    int e = q*4 + r, c = nb*16 + ln;
                    float a = relu_f(acc[nb][r] + ab2c[nb]);
                    float p = __expf(a);
                    Pf [e*PST + c] = p;
                    PMf[e*PST + c] = p * Mreg[nb*4 + r];   // write depends on MFMA -> ordered after t2 reads
                }
        }
        // ---- stage F: per-node reduction (wave's own 4 nodes, lane = channel)
        #pragma unroll
        for (int qn = 0; qn < 4; ++qn){
            int l  = w*4 + qn;
            int gs = max(s_off[l], ec);
            int ge = min(s_off[l+1], ec + cnt);
            float dd = den[qn], nn = num[qn];
            for (int g = gs; g < ge; ++g){
                int e = g - ec;
                dd += Pf [e*PST + lane];
                nn += PMf[e*PST + lane];
            }
            den[qn] = dd; num[qn] = nn;
        }
    }
    #pragma unroll
    for (int qn = 0; qn < 4; ++qn){
        int n = n0 + w*4 + qn;
        hout[(size_t)n * D + lane] = num[qn] / den[qn];
    }
}

// ---------------- pooling + classifier ----------------

__global__ __launch_bounds__(256) void k_pool(const float* __restrict__ h,
                                              const float* __restrict__ outW,
                                              const float* __restrict__ outb,
                                              float* __restrict__ out)
{
    __shared__ float sm[4][64];
    __shared__ float sp[2][64];
    int b = blockIdx.x;
    int t = threadIdx.x, j = t & 63, g = t >> 6;
    float mx = -1e30f;
    for (int r = b*2048 + g; r < (b+1)*2048; r += 4)
        mx = fmaxf(mx, h[(size_t)r * D + j]);
    sm[g][j] = mx;
    __syncthreads();
    if (t < 64){
        float m = fmaxf(fmaxf(sm[0][j], sm[1][j]), fmaxf(sm[2][j], sm[3][j]));
        sp[0][j] = m * outW[j*2 + 0];
        sp[1][j] = m * outW[j*2 + 1];
    }
    __syncthreads();
    if (t == 0){
        float s0 = outb[0], s1 = outb[1];
        for (int k = 0; k < 64; ++k){ s0 += sp[0][k]; s1 += sp[1][k]; }
        out[b*2]   = s0;
        out[b*2+1] = s1;
    }
}

// ---------------- launch ----------------

extern "C" void kernel_launch(void* const* d_in, const int* in_sizes, int n_in,
                              void* d_out, int out_size, void* d_ws, size_t ws_size,
                              hipStream_t stream)
{
    const float* x    = (const float*)d_in[0];
    const float* pos  = (const float*)d_in[1];
    const float* Wl   = (const float*)d_in[2];
    const float* Ws   = (const float*)d_in[3];
    const float* Wd   = (const float*)d_in[4];
    const float* pW1  = (const float*)d_in[5];
    const float* pb1  = (const float*)d_in[6];
    const float* pW2  = (const float*)d_in[7];
    const float* pb2  = (const float*)d_in[8];
    const float* aW1  = (const float*)d_in[9];
    const float* ab1  = (const float*)d_in[10];
    const float* aW2  = (const float*)d_in[11];
    const float* ab2  = (const float*)d_in[12];
    const float* outW = (const float*)d_in[13];
    const float* outb = (const float*)d_in[14];
    const int*   ei   = (const int*)d_in[15];
    float* out = (float*)d_out;

    char* wp = (char*)d_ws;
    auto alloc = [&](size_t bytes){
        void* p = (void*)wp;
        wp += (bytes + 255) & ~(size_t)255;
        return p;
    };
    int*   deg    = (int*)  alloc((size_t)N_NODES * 4);
    int*   part   = (int*)  alloc((size_t)N_NODES * 4);
    int*   bsum   = (int*)  alloc(1024);
    int*   bofs   = (int*)  alloc(1024);
    int*   off    = (int*)  alloc((size_t)(N_NODES + 1) * 4);
    int*   cursor = (int*)  alloc((size_t)N_NODES * 4);
    int*   srcs   = (int*)  alloc((size_t)N_EDGES * 4);
    float* pdb    = (float*)alloc((size_t)N_EDGES * 8);
    float* vv     = (float*)alloc((size_t)N_NODES * D * 4);
    float* as_    = (float*)alloc((size_t)N_NODES * D * 4);
    float* ad     = (float*)alloc((size_t)N_NODES * D * 4);
    float* h0     = (float*)alloc((size_t)N_NODES * D * 4);
    float* h1     = (float*)alloc((size_t)N_NODES * D * 4);
    unsigned short* bpk = (unsigned short*)alloc((size_t)NLAYERS * 24576 * 2);

    // sort edges by dst (counting sort)
    k_zero   <<<256,  256, 0, stream>>>(deg);
    k_hist   <<<4096, 256, 0, stream>>>(ei + N_EDGES, deg);
    k_scan1  <<<256,  256, 0, stream>>>(deg, part, bsum);
    k_scan2  <<<1,    256, 0, stream>>>(bsum, bofs);
    k_scan3  <<<256,  256, 0, stream>>>(part, bofs, off, cursor);
    k_scatter<<<4096, 256, 0, stream>>>(ei, pos, cursor, srcs, pdb);
    k_pack   <<<96,   256, 0, stream>>>(pW2, aW1, aW2, bpk);

    const float* hin = x;
    float* hbuf[2] = { h0, h1 };
    for (int L = 0; L < NLAYERS; ++L){
        float* hout = hbuf[L & 1];
        k_nodegemm<<<N_NODES/64, 256, 0, stream>>>(hin,
            Wl + (size_t)L*D*D, Ws + (size_t)L*D*D, Wd + (size_t)L*D*D,
            vv, as_, ad);
        k_edge<<<N_NODES/G, 256, 0, stream>>>(off, srcs, pdb, vv, as_, ad,
            pW1 + (size_t)L*2*D, pb1 + (size_t)L*D, pb2 + (size_t)L*D,
            ab1 + (size_t)L*D, ab2 + (size_t)L*D,
            bpk + (size_t)L*24576,
            hout);
        hin = hout;
    }
    k_pool<<<NB, 256, 0, stream>>>(hin, outW, outb, out);
}